// Round 4
// baseline (276.283 us; speedup 1.0000x reference)
//
#include <hip/hip_runtime.h>
#include <math.h>

#define NUM_E 8
#define DIM 4096
#define THREADS 256
#define WAVES (THREADS / 64)
#define VEC_ITERS (DIM / (THREADS * 4))   // 4
#define ROWS 4
#define GRID_B 2048

typedef float f32x4 __attribute__((ext_vector_type(4)));

__device__ __forceinline__ f32x4 nt_load4(const float* p) {
    return __builtin_nontemporal_load(reinterpret_cast<const f32x4*>(p));
}
__device__ __forceinline__ void nt_store4(float* p, f32x4 v) {
    __builtin_nontemporal_store(v, reinterpret_cast<f32x4*>(p));
}

// ---------------- Kernel A: gate logits + softmax -> ws[B][8] ----------------
__global__ __launch_bounds__(THREADS) void gate_weights_kernel(
    const float* __restrict__ x,   // [B, D]
    const float* __restrict__ W,   // [NUM, D]
    float* __restrict__ wgt_out)   // [B, NUM]
{
    const int b0   = blockIdx.x * ROWS;
    const int t    = threadIdx.x;
    const int lane = t & 63;
    const int wave = t >> 6;

    __shared__ float red[ROWS][WAVES][NUM_E];

#pragma unroll
    for (int r = 0; r < ROWS; ++r) {
        const float* __restrict__ xrow = x + (size_t)(b0 + r) * DIM;
        float p[NUM_E];
#pragma unroll
        for (int n = 0; n < NUM_E; ++n) p[n] = 0.0f;

#pragma unroll
        for (int i = 0; i < VEC_ITERS; ++i) {
            const int d = (i * THREADS + t) * 4;
            const f32x4 xv = nt_load4(xrow + d);
#pragma unroll
            for (int n = 0; n < NUM_E; ++n) {
                const f32x4 wv = *reinterpret_cast<const f32x4*>(W + n * DIM + d);
                p[n] += xv.x * wv.x + xv.y * wv.y + xv.z * wv.z + xv.w * wv.w;
            }
        }
#pragma unroll
        for (int n = 0; n < NUM_E; ++n) {
#pragma unroll
            for (int off = 32; off > 0; off >>= 1)
                p[n] += __shfl_down(p[n], off, 64);
        }
        if (lane == 0) {
#pragma unroll
            for (int n = 0; n < NUM_E; ++n) red[r][wave][n] = p[n];
        }
    }
    __syncthreads();

    // each wave finalizes one row (redundant within wave, lane 0 writes)
    {
        const int r = wave;  // WAVES == ROWS == 4
        float wgt[NUM_E];
#pragma unroll
        for (int n = 0; n < NUM_E; ++n) {
            float s = 0.0f;
#pragma unroll
            for (int w2 = 0; w2 < WAVES; ++w2) s += red[r][w2][n];
            wgt[n] = s;
        }
        float m = wgt[0];
#pragma unroll
        for (int n = 1; n < NUM_E; ++n) m = fmaxf(m, wgt[n]);
        float sum = 0.0f;
#pragma unroll
        for (int n = 0; n < NUM_E; ++n) {
            wgt[n] = __expf(wgt[n] - m);
            sum += wgt[n];
        }
        const float inv = 1.0f / sum;
        if (lane == 0) {
#pragma unroll
            for (int n = 0; n < NUM_E; ++n)
                wgt_out[(size_t)(b0 + r) * NUM_E + n] = wgt[n] * inv;
        }
    }
}

// ---------------- Kernel B: pure-stream weighted combine ----------------
__global__ __launch_bounds__(THREADS) void combine_kernel(
    const float* __restrict__ experts,  // [B, NUM, D]
    const float* __restrict__ wgt_in,   // [B, NUM]
    float* __restrict__ out,            // [B, D]
    int B)
{
    const int t = threadIdx.x;

    for (int b = blockIdx.x; b < B; b += GRID_B) {
        // broadcast-load the 8 weights (same address across threads, L2-hot)
        const f32x4 w0 = *reinterpret_cast<const f32x4*>(wgt_in + (size_t)b * NUM_E);
        const f32x4 w1 = *reinterpret_cast<const f32x4*>(wgt_in + (size_t)b * NUM_E + 4);
        float wgt[NUM_E] = {w0.x, w0.y, w0.z, w0.w, w1.x, w1.y, w1.z, w1.w};

        const float* __restrict__ erow = experts + (size_t)b * NUM_E * DIM;
        float* __restrict__ orow = out + (size_t)b * DIM;

#pragma unroll
        for (int i = 0; i < VEC_ITERS; ++i) {
            const int d = (i * THREADS + t) * 4;
            f32x4 acc = (f32x4)(0.0f);
#pragma unroll
            for (int n = 0; n < NUM_E; ++n) {
                const f32x4 ev = nt_load4(erow + (size_t)n * DIM + d);
                acc.x += wgt[n] * ev.x;
                acc.y += wgt[n] * ev.y;
                acc.z += wgt[n] * ev.z;
                acc.w += wgt[n] * ev.w;
            }
            nt_store4(orow + d, acc);
        }
    }
}

// ---------------- Fallback: fused (round-1 proven) ----------------
__global__ __launch_bounds__(THREADS) void gate_fused_kernel(
    const float* __restrict__ x,
    const float* __restrict__ experts,
    const float* __restrict__ W,
    float* __restrict__ out)
{
    const int b    = blockIdx.x;
    const int t    = threadIdx.x;
    const int lane = t & 63;
    const int wave = t >> 6;

    const float* __restrict__ xrow = x + (size_t)b * DIM;
    const float* __restrict__ erow = experts + (size_t)b * NUM_E * DIM;
    float* __restrict__ orow = out + (size_t)b * DIM;

    float p[NUM_E];
#pragma unroll
    for (int n = 0; n < NUM_E; ++n) p[n] = 0.0f;
#pragma unroll
    for (int i = 0; i < VEC_ITERS; ++i) {
        const int d = (i * THREADS + t) * 4;
        const f32x4 xv = *reinterpret_cast<const f32x4*>(xrow + d);
#pragma unroll
        for (int n = 0; n < NUM_E; ++n) {
            const f32x4 wv = *reinterpret_cast<const f32x4*>(W + n * DIM + d);
            p[n] += xv.x * wv.x + xv.y * wv.y + xv.z * wv.z + xv.w * wv.w;
        }
    }
#pragma unroll
    for (int n = 0; n < NUM_E; ++n) {
#pragma unroll
        for (int off = 32; off > 0; off >>= 1)
            p[n] += __shfl_down(p[n], off, 64);
    }
    __shared__ float red[WAVES * NUM_E];
    if (lane == 0) {
#pragma unroll
        for (int n = 0; n < NUM_E; ++n) red[wave * NUM_E + n] = p[n];
    }
    __syncthreads();
    float wgt[NUM_E];
#pragma unroll
    for (int n = 0; n < NUM_E; ++n) {
        float s = 0.0f;
#pragma unroll
        for (int w2 = 0; w2 < WAVES; ++w2) s += red[w2 * NUM_E + n];
        wgt[n] = s;
    }
    float m = wgt[0];
#pragma unroll
    for (int n = 1; n < NUM_E; ++n) m = fmaxf(m, wgt[n]);
    float sum = 0.0f;
#pragma unroll
    for (int n = 0; n < NUM_E; ++n) {
        wgt[n] = __expf(wgt[n] - m);
        sum += wgt[n];
    }
    const float inv = 1.0f / sum;
#pragma unroll
    for (int n = 0; n < NUM_E; ++n) wgt[n] *= inv;
#pragma unroll
    for (int i = 0; i < VEC_ITERS; ++i) {
        const int d = (i * THREADS + t) * 4;
        f32x4 acc = (f32x4)(0.0f);
#pragma unroll
        for (int n = 0; n < NUM_E; ++n) {
            const f32x4 ev = nt_load4(erow + (size_t)n * DIM + d);
            acc.x += wgt[n] * ev.x;
            acc.y += wgt[n] * ev.y;
            acc.z += wgt[n] * ev.z;
            acc.w += wgt[n] * ev.w;
        }
        nt_store4(orow + d, acc);
    }
}

extern "C" void kernel_launch(void* const* d_in, const int* in_sizes, int n_in,
                              void* d_out, int out_size, void* d_ws, size_t ws_size,
                              hipStream_t stream) {
    const float* x       = (const float*)d_in[0];
    const float* experts = (const float*)d_in[1];
    const float* W       = (const float*)d_in[2];
    float* out           = (float*)d_out;

    const int B = in_sizes[0] / DIM;   // 8192
    const size_t ws_needed = (size_t)B * NUM_E * sizeof(float);

    if (ws_size >= ws_needed) {
        float* wgt = (float*)d_ws;
        gate_weights_kernel<<<B / ROWS, THREADS, 0, stream>>>(x, W, wgt);
        combine_kernel<<<GRID_B, THREADS, 0, stream>>>(experts, wgt, out, B);
    } else {
        gate_fused_kernel<<<B, THREADS, 0, stream>>>(x, experts, W, out);
    }
}

// Round 5
// 237.502 us; speedup vs baseline: 1.1633x; 1.1633x over previous
//
#include <hip/hip_runtime.h>
#include <math.h>

#define NUM_E 8
#define DIM 4096
#define THREADS 256
#define WAVES 4
#define VEC_ITERS (DIM / (THREADS * 4))   // 4
#define ROWS 2

typedef float f32x4 __attribute__((ext_vector_type(4)));

__device__ __forceinline__ f32x4 nt_load4(const float* p) {
    return __builtin_nontemporal_load(reinterpret_cast<const f32x4*>(p));
}
__device__ __forceinline__ void nt_store4(float* p, f32x4 v) {
    __builtin_nontemporal_store(v, reinterpret_cast<f32x4*>(p));
}

// wave butterfly reduce + cross-wave LDS reduce + 8-wide softmax (redundant/thread)
__device__ __forceinline__ void reduce_softmax(float p[NUM_E],
                                               float (*red)[NUM_E],
                                               int lane, int wave,
                                               float wgt[NUM_E],
                                               bool pre_barrier)
{
#pragma unroll
    for (int n = 0; n < NUM_E; ++n) {
#pragma unroll
        for (int off = 32; off > 0; off >>= 1)
            p[n] += __shfl_down(p[n], off, 64);
    }
    if (pre_barrier) __syncthreads();   // WAR protection on red reuse
    if (lane == 0) {
#pragma unroll
        for (int n = 0; n < NUM_E; ++n) red[wave][n] = p[n];
    }
    __syncthreads();
#pragma unroll
    for (int n = 0; n < NUM_E; ++n)
        wgt[n] = red[0][n] + red[1][n] + red[2][n] + red[3][n];
    float m = wgt[0];
#pragma unroll
    for (int n = 1; n < NUM_E; ++n) m = fmaxf(m, wgt[n]);
    float sum = 0.0f;
#pragma unroll
    for (int n = 0; n < NUM_E; ++n) {
        wgt[n] = __expf(wgt[n] - m);
        sum += wgt[n];
    }
    const float inv = 1.0f / sum;
#pragma unroll
    for (int n = 0; n < NUM_E; ++n) wgt[n] *= inv;
}

__global__ __launch_bounds__(THREADS) void gate_pipelined_kernel(
    const float* __restrict__ x,        // [B, D]
    const float* __restrict__ experts,  // [B, NUM, D]
    const float* __restrict__ W,        // [NUM, D]
    float* __restrict__ out)            // [B, D]
{
    const int b0   = blockIdx.x * ROWS;
    const int t    = threadIdx.x;
    const int lane = t & 63;
    const int wave = t >> 6;

    __shared__ float red[WAVES][NUM_E];

    // ---- prologue: gate dot for row 0 ----
    const float* __restrict__ x0 = x + (size_t)b0 * DIM;
    float p[NUM_E];
#pragma unroll
    for (int n = 0; n < NUM_E; ++n) p[n] = 0.0f;
#pragma unroll
    for (int i = 0; i < VEC_ITERS; ++i) {
        const int d = (i * THREADS + t) * 4;
        const f32x4 xv = nt_load4(x0 + d);
#pragma unroll
        for (int n = 0; n < NUM_E; ++n) {
            const f32x4 wv = *reinterpret_cast<const f32x4*>(W + n * DIM + d);
            p[n] += xv.x * wv.x + xv.y * wv.y + xv.z * wv.z + xv.w * wv.w;
        }
    }
    float wgt0[NUM_E];
    reduce_softmax(p, red, lane, wave, wgt0, false);

    // ---- combine row 0, with row 1's gate dot interleaved (hidden under stream) ----
    const float* __restrict__ e0 = experts + (size_t)b0 * NUM_E * DIM;
    float* __restrict__ o0 = out + (size_t)b0 * DIM;
    const float* __restrict__ x1 = x + (size_t)(b0 + 1) * DIM;

    float p1[NUM_E];
#pragma unroll
    for (int n = 0; n < NUM_E; ++n) p1[n] = 0.0f;

#pragma unroll
    for (int i = 0; i < VEC_ITERS; ++i) {
        const int d = (i * THREADS + t) * 4;
        // row-1 gate work: x from HBM (1/9 of iter traffic), W from L2
        const f32x4 xv = nt_load4(x1 + d);
#pragma unroll
        for (int n = 0; n < NUM_E; ++n) {
            const f32x4 wv = *reinterpret_cast<const f32x4*>(W + n * DIM + d);
            p1[n] += xv.x * wv.x + xv.y * wv.y + xv.z * wv.z + xv.w * wv.w;
        }
        // row-0 combine stream
        f32x4 acc = (f32x4)(0.0f);
#pragma unroll
        for (int n = 0; n < NUM_E; ++n) {
            const f32x4 ev = nt_load4(e0 + (size_t)n * DIM + d);
            acc.x += wgt0[n] * ev.x;
            acc.y += wgt0[n] * ev.y;
            acc.z += wgt0[n] * ev.z;
            acc.w += wgt0[n] * ev.w;
        }
        nt_store4(o0 + d, acc);
    }

    float wgt1[NUM_E];
    reduce_softmax(p1, red, lane, wave, wgt1, true);

    // ---- combine row 1 ----
    const float* __restrict__ e1 = experts + (size_t)(b0 + 1) * NUM_E * DIM;
    float* __restrict__ o1 = out + (size_t)(b0 + 1) * DIM;

#pragma unroll
    for (int i = 0; i < VEC_ITERS; ++i) {
        const int d = (i * THREADS + t) * 4;
        f32x4 acc = (f32x4)(0.0f);
#pragma unroll
        for (int n = 0; n < NUM_E; ++n) {
            const f32x4 ev = nt_load4(e1 + (size_t)n * DIM + d);
            acc.x += wgt1[n] * ev.x;
            acc.y += wgt1[n] * ev.y;
            acc.z += wgt1[n] * ev.z;
            acc.w += wgt1[n] * ev.w;
        }
        nt_store4(o1 + d, acc);
    }
}

extern "C" void kernel_launch(void* const* d_in, const int* in_sizes, int n_in,
                              void* d_out, int out_size, void* d_ws, size_t ws_size,
                              hipStream_t stream) {
    const float* x       = (const float*)d_in[0];
    const float* experts = (const float*)d_in[1];
    const float* W       = (const float*)d_in[2];
    float* out           = (float*)d_out;

    const int B = in_sizes[0] / DIM;   // 8192

    gate_pipelined_kernel<<<B / ROWS, THREADS, 0, stream>>>(x, experts, W, out);
}

// Round 6
// 233.484 us; speedup vs baseline: 1.1833x; 1.0172x over previous
//
#include <hip/hip_runtime.h>
#include <math.h>

#define NUM_E 8
#define DIM 4096
#define THREADS 256
#define WAVES 4
#define VEC_ITERS (DIM / (THREADS * 4))   // 4
#define ROWS 2

typedef float f32x4 __attribute__((ext_vector_type(4)));

__device__ __forceinline__ f32x4 nt_load4(const float* p) {
    return __builtin_nontemporal_load(reinterpret_cast<const f32x4*>(p));
}
__device__ __forceinline__ void nt_store4(float* p, f32x4 v) {
    __builtin_nontemporal_store(v, reinterpret_cast<f32x4*>(p));
}

// wave butterfly reduce + cross-wave LDS reduce + 8-wide softmax (redundant/thread)
__device__ __forceinline__ void reduce_softmax(float p[NUM_E],
                                               float (*red)[NUM_E],
                                               int lane, int wave,
                                               float wgt[NUM_E],
                                               bool pre_barrier)
{
#pragma unroll
    for (int n = 0; n < NUM_E; ++n) {
#pragma unroll
        for (int off = 32; off > 0; off >>= 1)
            p[n] += __shfl_down(p[n], off, 64);
    }
    if (pre_barrier) __syncthreads();   // WAR protection on red reuse
    if (lane == 0) {
#pragma unroll
        for (int n = 0; n < NUM_E; ++n) red[wave][n] = p[n];
    }
    __syncthreads();
#pragma unroll
    for (int n = 0; n < NUM_E; ++n)
        wgt[n] = red[0][n] + red[1][n] + red[2][n] + red[3][n];
    float m = wgt[0];
#pragma unroll
    for (int n = 1; n < NUM_E; ++n) m = fmaxf(m, wgt[n]);
    float sum = 0.0f;
#pragma unroll
    for (int n = 0; n < NUM_E; ++n) {
        wgt[n] = __expf(wgt[n] - m);
        sum += wgt[n];
    }
    const float inv = 1.0f / sum;
#pragma unroll
    for (int n = 0; n < NUM_E; ++n) wgt[n] *= inv;
}

__global__ __launch_bounds__(THREADS) void gate_pipelined_kernel(
    const float* __restrict__ x,        // [B, D]
    const float* __restrict__ experts,  // [B, NUM, D]
    const float* __restrict__ W,        // [NUM, D]
    float* __restrict__ out)            // [B, D]
{
    const int b0   = blockIdx.x * ROWS;
    const int t    = threadIdx.x;
    const int lane = t & 63;
    const int wave = t >> 6;

    __shared__ float red[WAVES][NUM_E];

    // ---- prologue: gate dot for row 0 ----
    const float* __restrict__ x0 = x + (size_t)b0 * DIM;
    float p[NUM_E];
#pragma unroll
    for (int n = 0; n < NUM_E; ++n) p[n] = 0.0f;
#pragma unroll
    for (int i = 0; i < VEC_ITERS; ++i) {
        const int d = (i * THREADS + t) * 4;
        const f32x4 xv = nt_load4(x0 + d);
#pragma unroll
        for (int n = 0; n < NUM_E; ++n) {
            const f32x4 wv = *reinterpret_cast<const f32x4*>(W + n * DIM + d);
            p[n] += xv.x * wv.x + xv.y * wv.y + xv.z * wv.z + xv.w * wv.w;
        }
    }
    float wgt0[NUM_E];
    reduce_softmax(p, red, lane, wave, wgt0, false);

    // ---- combine row 0 (n-outer: sequential 128 KB expert sweep per block),
    //      with row 1's gate dot interleaved ----
    const float* __restrict__ e0 = experts + (size_t)b0 * NUM_E * DIM;
    float* __restrict__ o0 = out + (size_t)b0 * DIM;
    const float* __restrict__ x1 = x + (size_t)(b0 + 1) * DIM;

    // hoist row-1 x into registers (16 VGPRs)
    f32x4 xv[VEC_ITERS];
#pragma unroll
    for (int i = 0; i < VEC_ITERS; ++i)
        xv[i] = nt_load4(x1 + (i * THREADS + t) * 4);

    float p1[NUM_E];
#pragma unroll
    for (int n = 0; n < NUM_E; ++n) p1[n] = 0.0f;

    f32x4 acc[VEC_ITERS];
#pragma unroll
    for (int i = 0; i < VEC_ITERS; ++i) acc[i] = (f32x4)(0.0f);

#pragma unroll
    for (int n = 0; n < NUM_E; ++n) {
        const float wn = wgt0[n];
#pragma unroll
        for (int i = 0; i < VEC_ITERS; ++i) {
            const int d = (i * THREADS + t) * 4;
            const f32x4 ev = nt_load4(e0 + (size_t)n * DIM + d);
            acc[i].x += wn * ev.x;
            acc[i].y += wn * ev.y;
            acc[i].z += wn * ev.z;
            acc[i].w += wn * ev.w;
            // row-1 gate work (W from L2, rides under the stream)
            const f32x4 wv = *reinterpret_cast<const f32x4*>(W + n * DIM + d);
            p1[n] += xv[i].x * wv.x + xv[i].y * wv.y + xv[i].z * wv.z + xv[i].w * wv.w;
        }
    }
#pragma unroll
    for (int i = 0; i < VEC_ITERS; ++i)
        nt_store4(o0 + (i * THREADS + t) * 4, acc[i]);

    float wgt1[NUM_E];
    reduce_softmax(p1, red, lane, wave, wgt1, true);

    // ---- combine row 1 (n-outer, sequential sweep) ----
    const float* __restrict__ e1 = experts + (size_t)(b0 + 1) * NUM_E * DIM;
    float* __restrict__ o1 = out + (size_t)(b0 + 1) * DIM;

#pragma unroll
    for (int i = 0; i < VEC_ITERS; ++i) acc[i] = (f32x4)(0.0f);

#pragma unroll
    for (int n = 0; n < NUM_E; ++n) {
        const float wn = wgt1[n];
#pragma unroll
        for (int i = 0; i < VEC_ITERS; ++i) {
            const int d = (i * THREADS + t) * 4;
            const f32x4 ev = nt_load4(e1 + (size_t)n * DIM + d);
            acc[i].x += wn * ev.x;
            acc[i].y += wn * ev.y;
            acc[i].z += wn * ev.z;
            acc[i].w += wn * ev.w;
        }
    }
#pragma unroll
    for (int i = 0; i < VEC_ITERS; ++i)
        nt_store4(o1 + (i * THREADS + t) * 4, acc[i]);
}

extern "C" void kernel_launch(void* const* d_in, const int* in_sizes, int n_in,
                              void* d_out, int out_size, void* d_ws, size_t ws_size,
                              hipStream_t stream) {
    const float* x       = (const float*)d_in[0];
    const float* experts = (const float*)d_in[1];
    const float* W       = (const float*)d_in[2];
    float* out           = (float*)d_out;

    const int B = in_sizes[0] / DIM;   // 8192

    gate_pipelined_kernel<<<B / ROWS, THREADS, 0, stream>>>(x, experts, W, out);
}